// Round 6
// baseline (595.928 us; speedup 1.0000x reference)
//
#include <hip/hip_runtime.h>
#include <math.h>

#define HID 64
#define LN_EPS 1e-5f
#define NORM_EPS 1e-12f
#define CHUNK 1024
#define CONV_BLOCKS 2048

__device__ __forceinline__ float wave_sum64(float v) {
#pragma unroll
    for (int o = 32; o > 0; o >>= 1) v += __shfl_xor(v, o, 64);
    return v;
}

__device__ __forceinline__ int lower_bound_dev(const int* __restrict__ a, int n, int key) {
    int lo = 0, hi = n;
    while (lo < hi) {
        int mid = (lo + hi) >> 1;
        if (a[mid] < key) lo = mid + 1; else hi = mid;
    }
    return lo;
}

// ---------------- edge count (int histograms), 4 edges/thread ----------------
__global__ __launch_bounds__(256) void count_kernel(const int* __restrict__ src,
                                                    const int* __restrict__ dst,
                                                    int* __restrict__ cnt_out,
                                                    int* __restrict__ cnt_in,
                                                    int E) {
    int e0 = (blockIdx.x * 256 + threadIdx.x) * 4;
    if (e0 + 3 < E) {
        int4 s4 = *reinterpret_cast<const int4*>(src + e0);
        int4 d4 = *reinterpret_cast<const int4*>(dst + e0);
        atomicAdd(&cnt_out[s4.x], 1); atomicAdd(&cnt_out[s4.y], 1);
        atomicAdd(&cnt_out[s4.z], 1); atomicAdd(&cnt_out[s4.w], 1);
        atomicAdd(&cnt_in[d4.x], 1);  atomicAdd(&cnt_in[d4.y], 1);
        atomicAdd(&cnt_in[d4.z], 1);  atomicAdd(&cnt_in[d4.w], 1);
    } else {
        for (int e = e0; e < E; ++e) {
            atomicAdd(&cnt_out[src[e]], 1);
            atomicAdd(&cnt_in[dst[e]], 1);
        }
    }
}

// ---------------- scan1 + fused degree-norm ----------------
// per-chunk (1024) exclusive scan of cnt_in; also ns/nd from counts.
__global__ __launch_bounds__(256) void scan1_kernel(const int* __restrict__ cnt_in,
                                                    const int* __restrict__ cnt_out,
                                                    float* __restrict__ ns,
                                                    float* __restrict__ nd,
                                                    int* __restrict__ cs,
                                                    int* __restrict__ partials,
                                                    int N) {
    __shared__ int wsum[4];
    int t = threadIdx.x;
    int lane = t & 63, wave = t >> 6;
    int base = blockIdx.x * CHUNK + t * 4;
    int v0 = (base + 0 < N) ? cnt_in[base + 0] : 0;
    int v1 = (base + 1 < N) ? cnt_in[base + 1] : 0;
    int v2 = (base + 2 < N) ? cnt_in[base + 2] : 0;
    int v3 = (base + 3 < N) ? cnt_in[base + 3] : 0;

    // fused norm: ns from cnt_out, nd from cnt_in
    if (base + 3 < N) {
        int4 co = *reinterpret_cast<const int4*>(cnt_out + base);
        float4 nsv = make_float4(rsqrtf((float)max(co.x, 1)), rsqrtf((float)max(co.y, 1)),
                                 rsqrtf((float)max(co.z, 1)), rsqrtf((float)max(co.w, 1)));
        float4 ndv = make_float4(rsqrtf((float)max(v0, 1)), rsqrtf((float)max(v1, 1)),
                                 rsqrtf((float)max(v2, 1)), rsqrtf((float)max(v3, 1)));
        *reinterpret_cast<float4*>(ns + base) = nsv;
        *reinterpret_cast<float4*>(nd + base) = ndv;
    } else {
        for (int i = base; i < N; ++i) {
            ns[i] = rsqrtf((float)max(cnt_out[i], 1));
            nd[i] = rsqrtf((float)max(cnt_in[i], 1));
        }
    }

    int tsum = v0 + v1 + v2 + v3;
    int x = tsum;
#pragma unroll
    for (int off = 1; off < 64; off <<= 1) {
        int y = __shfl_up(x, off, 64);
        if (lane >= off) x += y;
    }
    if (lane == 63) wsum[wave] = x;
    __syncthreads();
    int waveoff = 0;
    for (int w = 0; w < wave; ++w) waveoff += wsum[w];
    int off0 = waveoff + x - tsum;
    if (base + 0 < N) cs[base + 0] = off0;
    if (base + 1 < N) cs[base + 1] = off0 + v0;
    if (base + 2 < N) cs[base + 2] = off0 + v0 + v1;
    if (base + 3 < N) cs[base + 3] = off0 + v0 + v1 + v2;
    if (t == 255) partials[blockIdx.x] = waveoff + x;  // block total
}

__global__ __launch_bounds__(256) void scan2_kernel(int* __restrict__ partials, int nch) {
    __shared__ int wsum[4];
    int t = threadIdx.x;
    int lane = t & 63, wave = t >> 6;
    int base = t * 4;
    int v0 = (base + 0 < nch) ? partials[base + 0] : 0;
    int v1 = (base + 1 < nch) ? partials[base + 1] : 0;
    int v2 = (base + 2 < nch) ? partials[base + 2] : 0;
    int v3 = (base + 3 < nch) ? partials[base + 3] : 0;
    int tsum = v0 + v1 + v2 + v3;
    int x = tsum;
#pragma unroll
    for (int off = 1; off < 64; off <<= 1) {
        int y = __shfl_up(x, off, 64);
        if (lane >= off) x += y;
    }
    if (lane == 63) wsum[wave] = x;
    __syncthreads();
    int waveoff = 0;
    for (int w = 0; w < wave; ++w) waveoff += wsum[w];
    int off0 = waveoff + x - tsum;
    if (base + 0 < nch) partials[base + 0] = off0;
    if (base + 1 < nch) partials[base + 1] = off0 + v0;
    if (base + 2 < nch) partials[base + 2] = off0 + v0 + v1;
    if (base + 3 < nch) partials[base + 3] = off0 + v0 + v1 + v2;
}

// scan3: finalize cs, init absolute cursor, write cs[N]=E
__global__ __launch_bounds__(256) void scan3_kernel(int* __restrict__ cs,
                                                    const int* __restrict__ partials,
                                                    int* __restrict__ cursor,
                                                    int N, int E) {
    int n = blockIdx.x * 256 + threadIdx.x;
    if (n < N) {
        int v = cs[n] + partials[n / CHUNK];
        cs[n] = v;
        cursor[n] = v;  // absolute cursor for fill
    }
    if (n == 0) cs[N] = E;
}

// ---------------- fill CSR buckets: epack[slot] = (src, ns[src]) ----------------
// cursor holds absolute positions; 4 edges/thread.
__global__ __launch_bounds__(256) void fill_kernel(const int* __restrict__ src,
                                                   const int* __restrict__ dst,
                                                   const float* __restrict__ ns,
                                                   int* __restrict__ cursor,
                                                   int2* __restrict__ epack,
                                                   int E) {
    int e0 = (blockIdx.x * 256 + threadIdx.x) * 4;
    if (e0 + 3 < E) {
        int4 s4 = *reinterpret_cast<const int4*>(src + e0);
        int4 d4 = *reinterpret_cast<const int4*>(dst + e0);
        float w0 = ns[s4.x], w1 = ns[s4.y], w2 = ns[s4.z], w3 = ns[s4.w];
        int p0 = atomicAdd(&cursor[d4.x], 1);
        int p1 = atomicAdd(&cursor[d4.y], 1);
        int p2 = atomicAdd(&cursor[d4.z], 1);
        int p3 = atomicAdd(&cursor[d4.w], 1);
        epack[p0] = make_int2(s4.x, __float_as_int(w0));
        epack[p1] = make_int2(s4.y, __float_as_int(w1));
        epack[p2] = make_int2(s4.z, __float_as_int(w2));
        epack[p3] = make_int2(s4.w, __float_as_int(w3));
    } else {
        for (int e = e0; e < E; ++e) {
            int s = src[e], d = dst[e];
            int p = atomicAdd(&cursor[d], 1);
            epack[p] = make_int2(s, __float_as_int(ns[s]));
        }
    }
}

// ---------------- fused conv: gather + (·nd)@W + b -> LN -> relu ----------------
// grid-stride, 4 waves/block, one wave per node; 4x MLP gather; 8 waves/EU forced.
__global__ __launch_bounds__(256, 8) void conv_kernel(const float* __restrict__ x,
                                                      const int2* __restrict__ epack,
                                                      const int* __restrict__ cs,
                                                      const float* __restrict__ nd,
                                                      const float* __restrict__ W,
                                                      const float* __restrict__ b,
                                                      const float* __restrict__ gam,
                                                      const float* __restrict__ bet,
                                                      float* __restrict__ out,
                                                      int N) {
    __shared__ float Ws[HID * HID];
    int tid = threadIdx.x;
#pragma unroll
    for (int i = tid; i < HID * HID / 4; i += 256) {
        reinterpret_cast<float4*>(Ws)[i] = reinterpret_cast<const float4*>(W)[i];
    }
    __syncthreads();
    int wave = tid >> 6;
    int lane = tid & 63;
    float bl = b[lane], gl = gam[lane], bel = bet[lane];

    for (int n = blockIdx.x * 4 + wave; n < N; n += CONV_BLOCKS * 4) {
        int beg = cs[n], end = cs[n + 1];
        float ndv = nd[n];
        float acc = 0.0f;
        int e = beg;
        for (; e + 4 <= end; e += 4) {
            int2 p0 = epack[e + 0];
            int2 p1 = epack[e + 1];
            int2 p2 = epack[e + 2];
            int2 p3 = epack[e + 3];
            float v0 = x[(size_t)p0.x * HID + lane];
            float v1 = x[(size_t)p1.x * HID + lane];
            float v2 = x[(size_t)p2.x * HID + lane];
            float v3 = x[(size_t)p3.x * HID + lane];
            acc = fmaf(v0, __int_as_float(p0.y), acc);
            acc = fmaf(v1, __int_as_float(p1.y), acc);
            acc = fmaf(v2, __int_as_float(p2.y), acc);
            acc = fmaf(v3, __int_as_float(p3.y), acc);
        }
        for (; e < end; ++e) {
            int2 p = epack[e];
            acc = fmaf(x[(size_t)p.x * HID + lane], __int_as_float(p.y), acc);
        }
        float t = acc * ndv;

        float y = bl;
#pragma unroll 8
        for (int k = 0; k < HID; ++k) {
            y = fmaf(__shfl(t, k, 64), Ws[k * HID + lane], y);
        }
        float mu = wave_sum64(y) * (1.0f / HID);
        float d = y - mu;
        float var = wave_sum64(d * d) * (1.0f / HID);
        float o = d * rsqrtf(var + LN_EPS) * gl + bel;
        o = fmaxf(o, 0.0f);
        out[(size_t)n * HID + lane] = o;
    }
}

// ---------------- atomic-free pooling: one block per graph (gid sorted) ----------------
__global__ __launch_bounds__(256) void pool_kernel(const float* __restrict__ h1,
                                                   const int* __restrict__ gid,
                                                   float* __restrict__ gsum,
                                                   float* __restrict__ gmaxf,
                                                   float* __restrict__ gcnt,
                                                   int N) {
    __shared__ float psum[4][HID];
    __shared__ float pmax[4][HID];
    __shared__ int se[2];
    int g = blockIdx.x;
    int tid = threadIdx.x;
    if (tid == 0) se[0] = lower_bound_dev(gid, N, g);
    if (tid == 64) se[1] = lower_bound_dev(gid, N, g + 1);
    __syncthreads();
    int s = se[0], e = se[1];
    int wave = tid >> 6, lane = tid & 63;
    float sum = 0.0f, mx = 0.0f;
    for (int r = s + wave; r < e; r += 4) {
        float v = h1[(size_t)r * HID + lane];
        sum += v;
        mx = fmaxf(mx, v);
    }
    psum[wave][lane] = sum;
    pmax[wave][lane] = mx;
    __syncthreads();
    if (tid < HID) {
        float ts = psum[0][tid] + psum[1][tid] + psum[2][tid] + psum[3][tid];
        float tm = fmaxf(fmaxf(pmax[0][tid], pmax[1][tid]), fmaxf(pmax[2][tid], pmax[3][tid]));
        gsum[(size_t)g * HID + tid] = ts;
        gmaxf[(size_t)g * HID + tid] = tm;
        if (tid == 0) gcnt[g] = (float)(e - s);
    }
}

// ---------------- head MLP: one wave per graph ----------------
__global__ __launch_bounds__(64) void head_kernel(const float* __restrict__ gsum,
                                                  const float* __restrict__ gmaxf,
                                                  const float* __restrict__ gcnt,
                                                  const float* __restrict__ Wc1,
                                                  const float* __restrict__ bc1,
                                                  const float* __restrict__ g3,
                                                  const float* __restrict__ be3,
                                                  const float* __restrict__ Wc2,
                                                  const float* __restrict__ bc2,
                                                  const float* __restrict__ g4,
                                                  const float* __restrict__ be4,
                                                  const float* __restrict__ Wc3,
                                                  const float* __restrict__ bc3,
                                                  float* __restrict__ out) {
    __shared__ float hg[2 * HID];
    __shared__ float t1[HID];
    int g = blockIdx.x;
    int lane = threadIdx.x;

    float cnt = fmaxf(gcnt[g], 1.0f);
    float mean = gsum[(size_t)g * HID + lane] / cnt;
    float mx = gmaxf[(size_t)g * HID + lane];

    float s1 = sqrtf(wave_sum64(mean * mean));
    float a = mean / fmaxf(s1, NORM_EPS);
    float s2 = sqrtf(wave_sum64(mx * mx));
    float bmx = mx / fmaxf(s2, NORM_EPS);

    hg[lane] = a;
    hg[HID + lane] = bmx;
    __syncthreads();

    float y = bc1[lane];
#pragma unroll 8
    for (int k = 0; k < 2 * HID; ++k) {
        y = fmaf(hg[k], Wc1[k * HID + lane], y);
    }
    float mu = wave_sum64(y) * (1.0f / HID);
    float d = y - mu;
    float var = wave_sum64(d * d) * (1.0f / HID);
    float o = d * rsqrtf(var + LN_EPS) * g3[lane] + be3[lane];
    o = fmaxf(o, 0.0f);
    t1[lane] = o;
    __syncthreads();

    float y2 = bc2[lane];
#pragma unroll 8
    for (int k = 0; k < HID; ++k) {
        y2 = fmaf(t1[k], Wc2[k * HID + lane], y2);
    }
    mu = wave_sum64(y2) * (1.0f / HID);
    d = y2 - mu;
    var = wave_sum64(d * d) * (1.0f / HID);
    o = d * rsqrtf(var + LN_EPS) * g4[lane] + be4[lane];
    o = fmaxf(o, 0.0f);

    float v = o * Wc3[lane];
    v = wave_sum64(v);
    if (lane == 0) out[g] = v + bc3[0];
}

extern "C" void kernel_launch(void* const* d_in, const int* in_sizes, int n_in,
                              void* d_out, int out_size, void* d_ws, size_t ws_size,
                              hipStream_t stream) {
    const float* h   = (const float*)d_in[0];
    const int*   src = (const int*)d_in[1];
    const int*   dst = (const int*)d_in[2];
    const int*   gid = (const int*)d_in[3];
    const float* W1  = (const float*)d_in[4];
    const float* b1  = (const float*)d_in[5];
    const float* W2  = (const float*)d_in[6];
    const float* b2  = (const float*)d_in[7];
    const float* g1  = (const float*)d_in[8];
    const float* be1 = (const float*)d_in[9];
    const float* g2  = (const float*)d_in[10];
    const float* be2 = (const float*)d_in[11];
    const float* g3  = (const float*)d_in[12];
    const float* be3 = (const float*)d_in[13];
    const float* g4  = (const float*)d_in[14];
    const float* be4 = (const float*)d_in[15];
    const float* Wc1 = (const float*)d_in[16];
    const float* bc1 = (const float*)d_in[17];
    const float* Wc2 = (const float*)d_in[18];
    const float* bc2 = (const float*)d_in[19];
    const float* Wc3 = (const float*)d_in[20];
    const float* bc3 = (const float*)d_in[21];
    float* out = (float*)d_out;

    const int N = in_sizes[0] / HID;   // 100000
    const int E = in_sizes[1];         // 1200000
    const int G = out_size;            // 512

    // workspace layout (8B-aligned large arrays first)
    char* ws = (char*)d_ws;
    float* h1     = (float*)ws;                                  // N*64 f
    float* h2     = h1 + (size_t)N * HID;                        // N*64 f
    int2*  epack  = (int2*)(h2 + (size_t)N * HID);               // E int2
    float* ns     = (float*)(epack + E);                         // N f
    float* nd     = ns + N;                                      // N f
    int*   cnt_out= (int*)(nd + N);                              // N i (becomes cursor)
    int*   cnt_in = cnt_out + N;                                 // N i
    int*   cs     = cnt_in + N;                                  // N+1 i
    int*   partials = cs + N + 4;                                // 1024 i
    float* gsum   = (float*)(partials + 1024);                   // G*64 f
    float* gmaxf  = gsum + (size_t)G * HID;                      // G*64 f
    float* gcnt   = gmaxf + (size_t)G * HID;                     // G f

    const int nch = (N + CHUNK - 1) / CHUNK;
    const int E4 = (E + 3) / 4;

    // zero the two histograms (contiguous 2N ints); pooling buffers written fully by pool
    hipMemsetAsync(cnt_out, 0, sizeof(int) * (size_t)2 * N, stream);

    // CSR build
    count_kernel<<<(E4 + 255) / 256, 256, 0, stream>>>(src, dst, cnt_out, cnt_in, E);
    scan1_kernel<<<nch, 256, 0, stream>>>(cnt_in, cnt_out, ns, nd, cs, partials, N);
    scan2_kernel<<<1, 256, 0, stream>>>(partials, nch);
    scan3_kernel<<<(N + 255) / 256, 256, 0, stream>>>(cs, partials, cnt_out, N, E);
    fill_kernel<<<(E4 + 255) / 256, 256, 0, stream>>>(src, dst, ns, cnt_out, epack, E);

    // conv1: h -> h1 ; conv2: h1 -> h2
    conv_kernel<<<CONV_BLOCKS, 256, 0, stream>>>(h, epack, cs, nd, W1, b1, g1, be1, h1, N);
    conv_kernel<<<CONV_BLOCKS, 256, 0, stream>>>(h1, epack, cs, nd, W2, b2, g2, be2, h2, N);

    // atomic-free pooling: one block per graph
    pool_kernel<<<G, 256, 0, stream>>>(h2, gid, gsum, gmaxf, gcnt, N);

    // head
    head_kernel<<<G, 64, 0, stream>>>(gsum, gmaxf, gcnt, Wc1, bc1, g3, be3,
                                      Wc2, bc2, g4, be4, Wc3, bc3, out);
}

// Round 8
// 577.222 us; speedup vs baseline: 1.0324x; 1.0324x over previous
//
#include <hip/hip_runtime.h>
#include <math.h>

#define HID 64
#define LN_EPS 1e-5f
#define NORM_EPS 1e-12f
#define CHUNK 1024
#define CONV_BLOCKS 2048

typedef _Float16 half4v __attribute__((ext_vector_type(4)));

__device__ __forceinline__ float wave_sum64(float v) {
#pragma unroll
    for (int o = 32; o > 0; o >>= 1) v += __shfl_xor(v, o, 64);
    return v;
}

__device__ __forceinline__ int lower_bound_dev(const int* __restrict__ a, int n, int key) {
    int lo = 0, hi = n;
    while (lo < hi) {
        int mid = (lo + hi) >> 1;
        if (a[mid] < key) lo = mid + 1; else hi = mid;
    }
    return lo;
}

// ---------------- edge count (int histograms), 4 edges/thread ----------------
__global__ __launch_bounds__(256) void count_kernel(const int* __restrict__ src,
                                                    const int* __restrict__ dst,
                                                    int* __restrict__ cnt_out,
                                                    int* __restrict__ cnt_in,
                                                    int E) {
    int e0 = (blockIdx.x * 256 + threadIdx.x) * 4;
    if (e0 + 3 < E) {
        int4 s4 = *reinterpret_cast<const int4*>(src + e0);
        int4 d4 = *reinterpret_cast<const int4*>(dst + e0);
        atomicAdd(&cnt_out[s4.x], 1); atomicAdd(&cnt_out[s4.y], 1);
        atomicAdd(&cnt_out[s4.z], 1); atomicAdd(&cnt_out[s4.w], 1);
        atomicAdd(&cnt_in[d4.x], 1);  atomicAdd(&cnt_in[d4.y], 1);
        atomicAdd(&cnt_in[d4.z], 1);  atomicAdd(&cnt_in[d4.w], 1);
    } else {
        for (int e = e0; e < E; ++e) {
            atomicAdd(&cnt_out[src[e]], 1);
            atomicAdd(&cnt_in[dst[e]], 1);
        }
    }
}

// ---------------- scan1 + fused degree-norm ----------------
__global__ __launch_bounds__(256) void scan1_kernel(const int* __restrict__ cnt_in,
                                                    const int* __restrict__ cnt_out,
                                                    float* __restrict__ ns,
                                                    float* __restrict__ nd,
                                                    int* __restrict__ cs,
                                                    int* __restrict__ partials,
                                                    int N) {
    __shared__ int wsum[4];
    int t = threadIdx.x;
    int lane = t & 63, wave = t >> 6;
    int base = blockIdx.x * CHUNK + t * 4;
    int v0 = (base + 0 < N) ? cnt_in[base + 0] : 0;
    int v1 = (base + 1 < N) ? cnt_in[base + 1] : 0;
    int v2 = (base + 2 < N) ? cnt_in[base + 2] : 0;
    int v3 = (base + 3 < N) ? cnt_in[base + 3] : 0;

    if (base + 3 < N) {
        int4 co = *reinterpret_cast<const int4*>(cnt_out + base);
        float4 nsv = make_float4(rsqrtf((float)max(co.x, 1)), rsqrtf((float)max(co.y, 1)),
                                 rsqrtf((float)max(co.z, 1)), rsqrtf((float)max(co.w, 1)));
        float4 ndv = make_float4(rsqrtf((float)max(v0, 1)), rsqrtf((float)max(v1, 1)),
                                 rsqrtf((float)max(v2, 1)), rsqrtf((float)max(v3, 1)));
        *reinterpret_cast<float4*>(ns + base) = nsv;
        *reinterpret_cast<float4*>(nd + base) = ndv;
    } else {
        for (int i = base; i < N; ++i) {
            ns[i] = rsqrtf((float)max(cnt_out[i], 1));
            nd[i] = rsqrtf((float)max(cnt_in[i], 1));
        }
    }

    int tsum = v0 + v1 + v2 + v3;
    int x = tsum;
#pragma unroll
    for (int off = 1; off < 64; off <<= 1) {
        int y = __shfl_up(x, off, 64);
        if (lane >= off) x += y;
    }
    if (lane == 63) wsum[wave] = x;
    __syncthreads();
    int waveoff = 0;
    for (int w = 0; w < wave; ++w) waveoff += wsum[w];
    int off0 = waveoff + x - tsum;
    if (base + 0 < N) cs[base + 0] = off0;
    if (base + 1 < N) cs[base + 1] = off0 + v0;
    if (base + 2 < N) cs[base + 2] = off0 + v0 + v1;
    if (base + 3 < N) cs[base + 3] = off0 + v0 + v1 + v2;
    if (t == 255) partials[blockIdx.x] = waveoff + x;
}

__global__ __launch_bounds__(256) void scan2_kernel(int* __restrict__ partials, int nch) {
    __shared__ int wsum[4];
    int t = threadIdx.x;
    int lane = t & 63, wave = t >> 6;
    int base = t * 4;
    int v0 = (base + 0 < nch) ? partials[base + 0] : 0;
    int v1 = (base + 1 < nch) ? partials[base + 1] : 0;
    int v2 = (base + 2 < nch) ? partials[base + 2] : 0;
    int v3 = (base + 3 < nch) ? partials[base + 3] : 0;
    int tsum = v0 + v1 + v2 + v3;
    int x = tsum;
#pragma unroll
    for (int off = 1; off < 64; off <<= 1) {
        int y = __shfl_up(x, off, 64);
        if (lane >= off) x += y;
    }
    if (lane == 63) wsum[wave] = x;
    __syncthreads();
    int waveoff = 0;
    for (int w = 0; w < wave; ++w) waveoff += wsum[w];
    int off0 = waveoff + x - tsum;
    if (base + 0 < nch) partials[base + 0] = off0;
    if (base + 1 < nch) partials[base + 1] = off0 + v0;
    if (base + 2 < nch) partials[base + 2] = off0 + v0 + v1;
    if (base + 3 < nch) partials[base + 3] = off0 + v0 + v1 + v2;
}

// scan3: finalize cs, init absolute cursor, write cs[N]=E
__global__ __launch_bounds__(256) void scan3_kernel(int* __restrict__ cs,
                                                    const int* __restrict__ partials,
                                                    int* __restrict__ cursor,
                                                    int N, int E) {
    int n = blockIdx.x * 256 + threadIdx.x;
    if (n < N) {
        int v = cs[n] + partials[n / CHUNK];
        cs[n] = v;
        cursor[n] = v;
    }
    if (n == 0) cs[N] = E;
}

// ---------------- prescale: xs[n][d] = h[n][d] * ns[n] as fp16 ----------------
__global__ __launch_bounds__(256) void prescale_kernel(const float* __restrict__ x,
                                                       const float* __restrict__ ns,
                                                       _Float16* __restrict__ xs,
                                                       int total) {
    int i = (blockIdx.x * 256 + threadIdx.x) * 4;
    if (i >= total) return;
    float w = ns[i >> 6];
    float4 v = *reinterpret_cast<const float4*>(x + i);
    half4v o;
    o.x = (_Float16)(v.x * w);
    o.y = (_Float16)(v.y * w);
    o.z = (_Float16)(v.z * w);
    o.w = (_Float16)(v.w * w);
    *reinterpret_cast<half4v*>(xs + i) = o;
}

// ---------------- fill CSR buckets: eidx[slot] = src ----------------
__global__ __launch_bounds__(256) void fill_kernel(const int* __restrict__ src,
                                                   const int* __restrict__ dst,
                                                   int* __restrict__ cursor,
                                                   int* __restrict__ eidx,
                                                   int E) {
    int e0 = (blockIdx.x * 256 + threadIdx.x) * 4;
    if (e0 + 3 < E) {
        int4 s4 = *reinterpret_cast<const int4*>(src + e0);
        int4 d4 = *reinterpret_cast<const int4*>(dst + e0);
        int p0 = atomicAdd(&cursor[d4.x], 1);
        int p1 = atomicAdd(&cursor[d4.y], 1);
        int p2 = atomicAdd(&cursor[d4.z], 1);
        int p3 = atomicAdd(&cursor[d4.w], 1);
        eidx[p0] = s4.x;
        eidx[p1] = s4.y;
        eidx[p2] = s4.z;
        eidx[p3] = s4.w;
    } else {
        for (int e = e0; e < E; ++e) {
            int p = atomicAdd(&cursor[dst[e]], 1);
            eidx[p] = src[e];
        }
    }
}

// ---------------- fused conv: fp16 gather + (·nd)@W + b -> LN -> relu ----------------
// MODE 0: write f32 out. MODE 1: write fp16 out scaled by ns (input for next conv).
template <int MODE>
__global__ __launch_bounds__(256, 8) void conv_kernel(const _Float16* __restrict__ xs,
                                                      const int* __restrict__ eidx,
                                                      const int* __restrict__ cs,
                                                      const float* __restrict__ nd,
                                                      const float* __restrict__ ns,
                                                      const float* __restrict__ W,
                                                      const float* __restrict__ b,
                                                      const float* __restrict__ gam,
                                                      const float* __restrict__ bet,
                                                      void* __restrict__ outp,
                                                      int N) {
    __shared__ float Ws[HID * HID];
    int tid = threadIdx.x;
#pragma unroll
    for (int i = tid; i < HID * HID / 4; i += 256) {
        reinterpret_cast<float4*>(Ws)[i] = reinterpret_cast<const float4*>(W)[i];
    }
    __syncthreads();
    int wave = tid >> 6;
    int lane = tid & 63;
    float bl = b[lane], gl = gam[lane], bel = bet[lane];

    for (int n = blockIdx.x * 4 + wave; n < N; n += CONV_BLOCKS * 4) {
        int beg = cs[n], end = cs[n + 1];
        float acc = 0.0f;
        int e = beg;
        for (; e + 4 <= end; e += 4) {
            int s0 = eidx[e + 0];
            int s1 = eidx[e + 1];
            int s2 = eidx[e + 2];
            int s3 = eidx[e + 3];
            float v0 = (float)xs[(size_t)s0 * HID + lane];
            float v1 = (float)xs[(size_t)s1 * HID + lane];
            float v2 = (float)xs[(size_t)s2 * HID + lane];
            float v3 = (float)xs[(size_t)s3 * HID + lane];
            acc += (v0 + v1) + (v2 + v3);
        }
        for (; e < end; ++e) {
            acc += (float)xs[(size_t)eidx[e] * HID + lane];
        }
        float t = acc * nd[n];

        float y = bl;
#pragma unroll 8
        for (int k = 0; k < HID; ++k) {
            y = fmaf(__shfl(t, k, 64), Ws[k * HID + lane], y);
        }
        float mu = wave_sum64(y) * (1.0f / HID);
        float d = y - mu;
        float var = wave_sum64(d * d) * (1.0f / HID);
        float o = d * rsqrtf(var + LN_EPS) * gl + bel;
        o = fmaxf(o, 0.0f);
        if (MODE == 1) {
            ((_Float16*)outp)[(size_t)n * HID + lane] = (_Float16)(o * ns[n]);
        } else {
            ((float*)outp)[(size_t)n * HID + lane] = o;
        }
    }
}

// ---------------- atomic-free pooling: one block per graph (gid sorted) ----------------
__global__ __launch_bounds__(256) void pool_kernel(const float* __restrict__ h1,
                                                   const int* __restrict__ gid,
                                                   float* __restrict__ gsum,
                                                   float* __restrict__ gmaxf,
                                                   float* __restrict__ gcnt,
                                                   int N) {
    __shared__ float psum[4][HID];
    __shared__ float pmax[4][HID];
    __shared__ int se[2];
    int g = blockIdx.x;
    int tid = threadIdx.x;
    if (tid == 0) se[0] = lower_bound_dev(gid, N, g);
    if (tid == 64) se[1] = lower_bound_dev(gid, N, g + 1);
    __syncthreads();
    int s = se[0], e = se[1];
    int wave = tid >> 6, lane = tid & 63;
    float sum = 0.0f, mx = 0.0f;
    for (int r = s + wave; r < e; r += 4) {
        float v = h1[(size_t)r * HID + lane];
        sum += v;
        mx = fmaxf(mx, v);
    }
    psum[wave][lane] = sum;
    pmax[wave][lane] = mx;
    __syncthreads();
    if (tid < HID) {
        float ts = psum[0][tid] + psum[1][tid] + psum[2][tid] + psum[3][tid];
        float tm = fmaxf(fmaxf(pmax[0][tid], pmax[1][tid]), fmaxf(pmax[2][tid], pmax[3][tid]));
        gsum[(size_t)g * HID + tid] = ts;
        gmaxf[(size_t)g * HID + tid] = tm;
        if (tid == 0) gcnt[g] = (float)(e - s);
    }
}

// ---------------- head MLP: one wave per graph ----------------
__global__ __launch_bounds__(64) void head_kernel(const float* __restrict__ gsum,
                                                  const float* __restrict__ gmaxf,
                                                  const float* __restrict__ gcnt,
                                                  const float* __restrict__ Wc1,
                                                  const float* __restrict__ bc1,
                                                  const float* __restrict__ g3,
                                                  const float* __restrict__ be3,
                                                  const float* __restrict__ Wc2,
                                                  const float* __restrict__ bc2,
                                                  const float* __restrict__ g4,
                                                  const float* __restrict__ be4,
                                                  const float* __restrict__ Wc3,
                                                  const float* __restrict__ bc3,
                                                  float* __restrict__ out) {
    __shared__ float hg[2 * HID];
    __shared__ float t1[HID];
    int g = blockIdx.x;
    int lane = threadIdx.x;

    float cnt = fmaxf(gcnt[g], 1.0f);
    float mean = gsum[(size_t)g * HID + lane] / cnt;
    float mx = gmaxf[(size_t)g * HID + lane];

    float s1 = sqrtf(wave_sum64(mean * mean));
    float a = mean / fmaxf(s1, NORM_EPS);
    float s2 = sqrtf(wave_sum64(mx * mx));
    float bmx = mx / fmaxf(s2, NORM_EPS);

    hg[lane] = a;
    hg[HID + lane] = bmx;
    __syncthreads();

    float y = bc1[lane];
#pragma unroll 8
    for (int k = 0; k < 2 * HID; ++k) {
        y = fmaf(hg[k], Wc1[k * HID + lane], y);
    }
    float mu = wave_sum64(y) * (1.0f / HID);
    float d = y - mu;
    float var = wave_sum64(d * d) * (1.0f / HID);
    float o = d * rsqrtf(var + LN_EPS) * g3[lane] + be3[lane];
    o = fmaxf(o, 0.0f);
    t1[lane] = o;
    __syncthreads();

    float y2 = bc2[lane];
#pragma unroll 8
    for (int k = 0; k < HID; ++k) {
        y2 = fmaf(t1[k], Wc2[k * HID + lane], y2);
    }
    mu = wave_sum64(y2) * (1.0f / HID);
    d = y2 - mu;
    var = wave_sum64(d * d) * (1.0f / HID);
    o = d * rsqrtf(var + LN_EPS) * g4[lane] + be4[lane];
    o = fmaxf(o, 0.0f);

    float v = o * Wc3[lane];
    v = wave_sum64(v);
    if (lane == 0) out[g] = v + bc3[0];
}

extern "C" void kernel_launch(void* const* d_in, const int* in_sizes, int n_in,
                              void* d_out, int out_size, void* d_ws, size_t ws_size,
                              hipStream_t stream) {
    const float* h   = (const float*)d_in[0];
    const int*   src = (const int*)d_in[1];
    const int*   dst = (const int*)d_in[2];
    const int*   gid = (const int*)d_in[3];
    const float* W1  = (const float*)d_in[4];
    const float* b1  = (const float*)d_in[5];
    const float* W2  = (const float*)d_in[6];
    const float* b2  = (const float*)d_in[7];
    const float* g1  = (const float*)d_in[8];
    const float* be1 = (const float*)d_in[9];
    const float* g2  = (const float*)d_in[10];
    const float* be2 = (const float*)d_in[11];
    const float* g3  = (const float*)d_in[12];
    const float* be3 = (const float*)d_in[13];
    const float* g4  = (const float*)d_in[14];
    const float* be4 = (const float*)d_in[15];
    const float* Wc1 = (const float*)d_in[16];
    const float* bc1 = (const float*)d_in[17];
    const float* Wc2 = (const float*)d_in[18];
    const float* bc2 = (const float*)d_in[19];
    const float* Wc3 = (const float*)d_in[20];
    const float* bc3 = (const float*)d_in[21];
    float* out = (float*)d_out;

    const int N = in_sizes[0] / HID;   // 100000
    const int E = in_sizes[1];         // 1200000
    const int G = out_size;            // 512

    // workspace layout
    char* ws = (char*)d_ws;
    _Float16* xs1 = (_Float16*)ws;                               // N*64 f16
    _Float16* xs2 = xs1 + (size_t)N * HID;                       // N*64 f16
    float* h2     = (float*)(xs2 + (size_t)N * HID);             // N*64 f
    int*   eidx   = (int*)(h2 + (size_t)N * HID);                // E i
    float* ns     = (float*)(eidx + E);                          // N f
    float* nd     = ns + N;                                      // N f
    int*   cnt_out= (int*)(nd + N);                              // N i (becomes cursor)
    int*   cnt_in = cnt_out + N;                                 // N i
    int*   cs     = cnt_in + N;                                  // N+1 i
    int*   partials = cs + N + 4;                                // 1024 i
    float* gsum   = (float*)(partials + 1024);                   // G*64 f
    float* gmaxf  = gsum + (size_t)G * HID;                      // G*64 f
    float* gcnt   = gmaxf + (size_t)G * HID;                     // G f

    const int nch = (N + CHUNK - 1) / CHUNK;
    const int E4 = (E + 3) / 4;
    const int total = N * HID;

    hipMemsetAsync(cnt_out, 0, sizeof(int) * (size_t)2 * N, stream);

    // CSR build + prescale
    count_kernel<<<(E4 + 255) / 256, 256, 0, stream>>>(src, dst, cnt_out, cnt_in, E);
    scan1_kernel<<<nch, 256, 0, stream>>>(cnt_in, cnt_out, ns, nd, cs, partials, N);
    scan2_kernel<<<1, 256, 0, stream>>>(partials, nch);
    scan3_kernel<<<(N + 255) / 256, 256, 0, stream>>>(cs, partials, cnt_out, N, E);
    prescale_kernel<<<(total / 4 + 255) / 256, 256, 0, stream>>>(h, ns, xs1, total);
    fill_kernel<<<(E4 + 255) / 256, 256, 0, stream>>>(src, dst, cnt_out, eidx, E);

    // conv1: xs1 -> xs2 (fp16, pre-scaled by ns) ; conv2: xs2 -> h2 (f32)
    conv_kernel<1><<<CONV_BLOCKS, 256, 0, stream>>>(xs1, eidx, cs, nd, ns, W1, b1, g1, be1, xs2, N);
    conv_kernel<0><<<CONV_BLOCKS, 256, 0, stream>>>(xs2, eidx, cs, nd, ns, W2, b2, g2, be2, h2, N);

    // atomic-free pooling: one block per graph
    pool_kernel<<<G, 256, 0, stream>>>(h2, gid, gsum, gmaxf, gcnt, N);

    // head
    head_kernel<<<G, 64, 0, stream>>>(gsum, gmaxf, gcnt, Wc1, bc1, g3, be3,
                                      Wc2, bc2, g4, be4, Wc3, bc3, out);
}